// Round 2
// baseline (866.518 us; speedup 1.0000x reference)
//
#include <hip/hip_runtime.h>
#include <hip/hip_bf16.h>

#define N_NODES 50000
#define N_EDGES 800000
#define POOL_BLOCKS 2048
#define NB 196  // ceil(N_NODES/256)

// ---------------- CSR build ----------------
__global__ void k_hist(const int* __restrict__ dst, int* __restrict__ counts) {
    int e = blockIdx.x * 256 + threadIdx.x;
    if (e < N_EDGES) atomicAdd(&counts[dst[e]], 1);
}

// per-256-block inclusive scan -> local exclusive in row_ptr, block totals in partial
__global__ __launch_bounds__(256) void k_scan1(const int* __restrict__ counts,
                                               int* __restrict__ row_ptr,
                                               int* __restrict__ partial) {
    __shared__ int sd[256];
    int t = threadIdx.x, i = blockIdx.x * 256 + t;
    int v = (i < N_NODES) ? counts[i] : 0;
    sd[t] = v;
    __syncthreads();
    for (int off = 1; off < 256; off <<= 1) {
        int o = (t >= off) ? sd[t - off] : 0;
        __syncthreads();
        sd[t] += o;
        __syncthreads();
    }
    if (i < N_NODES) row_ptr[i] = sd[t] - v;   // local exclusive
    if (t == 255) partial[blockIdx.x] = sd[255];
}

// single block: exclusive scan of NB block totals; total -> row_ptr[N]
__global__ __launch_bounds__(256) void k_scan2(int* __restrict__ partial,
                                               int* __restrict__ row_ptr) {
    __shared__ int sd[256];
    int t = threadIdx.x;
    int v = (t < NB) ? partial[t] : 0;
    sd[t] = v;
    __syncthreads();
    for (int off = 1; off < 256; off <<= 1) {
        int o = (t >= off) ? sd[t - off] : 0;
        __syncthreads();
        sd[t] += o;
        __syncthreads();
    }
    if (t < NB) partial[t] = sd[t] - v;        // exclusive block base
    if (t == NB - 1) row_ptr[N_NODES] = sd[t];
}

__global__ __launch_bounds__(256) void k_scan3(int* __restrict__ row_ptr,
                                               const int* __restrict__ partial,
                                               int* __restrict__ cursor) {
    int i = blockIdx.x * 256 + threadIdx.x;
    if (i < N_NODES) {
        int v = row_ptr[i] + partial[blockIdx.x];
        row_ptr[i] = v;
        cursor[i] = v;
    }
}

__global__ void k_scatter(const int* __restrict__ src, const int* __restrict__ dst,
                          int* __restrict__ cursor, int* __restrict__ src_sorted) {
    int e = blockIdx.x * 256 + threadIdx.x;
    if (e < N_EDGES) {
        int d = dst[e];
        int pos = atomicAdd(&cursor[d], 1);
        src_sorted[pos] = src[e];
    }
}

// ---------------- projection GEMM: out = relu(hin @ w + b), fp32 ----------------
template<int K, int C, int BLOCK>
__global__ __launch_bounds__(BLOCK) void k_proj(const float* __restrict__ hin,
                                                const float* __restrict__ w,
                                                const float* __restrict__ b,
                                                float* __restrict__ out) {
    constexpr int R = 8;
    constexpr int NC = C / BLOCK;
    __shared__ __align__(16) float hls[R * K];
    int t = threadIdx.x;
    int ch = blockIdx.x;  // grid == N_NODES/R
    int base = ch * R * K;
    for (int i = t; i < R * K; i += BLOCK) hls[i] = hin[base + i];
    __syncthreads();
    float acc[NC][R];
#pragma unroll
    for (int nc = 0; nc < NC; ++nc) {
        float bv = b[t + nc * BLOCK];
#pragma unroll
        for (int r = 0; r < R; ++r) acc[nc][r] = bv;
    }
    for (int k4 = 0; k4 < K / 4; ++k4) {
        float4 hv[R];
#pragma unroll
        for (int r = 0; r < R; ++r) hv[r] = *(const float4*)&hls[r * K + k4 * 4];
#pragma unroll
        for (int j = 0; j < 4; ++j) {
            int k = k4 * 4 + j;
            float wv[NC];
#pragma unroll
            for (int nc = 0; nc < NC; ++nc) wv[nc] = w[k * C + t + nc * BLOCK];
#pragma unroll
            for (int r = 0; r < R; ++r) {
                float hvr = (j == 0) ? hv[r].x : (j == 1) ? hv[r].y : (j == 2) ? hv[r].z : hv[r].w;
#pragma unroll
                for (int nc = 0; nc < NC; ++nc) acc[nc][r] = fmaf(hvr, wv[nc], acc[nc][r]);
            }
        }
    }
#pragma unroll
    for (int r = 0; r < R; ++r)
#pragma unroll
        for (int nc = 0; nc < NC; ++nc)
            out[(ch * R + r) * C + t + nc * BLOCK] = fmaxf(acc[nc][r], 0.f);
}

// ---------------- segment softmax aggregation (online) ----------------
template<int C>
__global__ __launch_bounds__(C) void k_aggr(const float* __restrict__ xp,
                                            const float* __restrict__ tvec,
                                            const int* __restrict__ row_ptr,
                                            const int* __restrict__ srcs,
                                            float* __restrict__ aggr) {
    int c = threadIdx.x;
    float tv = tvec[c];
    int n = blockIdx.x;
    int beg = row_ptr[n], end = row_ptr[n + 1];
    float m = -INFINITY, se = 0.f, sem = 0.f;
    int e = beg;
    float nxt = 0.f;
    if (e < end) { int s = srcs[e]; nxt = xp[(size_t)s * C + c]; }
    for (; e < end; ++e) {
        float msg = nxt;
        if (e + 1 < end) { int s2 = srcs[e + 1]; nxt = xp[(size_t)s2 * C + c]; }
        float logit = msg * tv;
        float mn = fmaxf(m, logit);
        float sc = __expf(m - mn);
        float wgt = __expf(logit - mn);
        se = se * sc + wgt;
        sem = sem * sc + wgt * msg;
        m = mn;
    }
    aggr[(size_t)n * C + c] = sem / fmaxf(se, 1e-16f);
}

// ---------------- out = relu(l2norm(aggr@wl + bl + x@wr)), fp32 ----------------
template<int K, int C>
__global__ __launch_bounds__(128) void k_out(const float* __restrict__ aggr,
                                             const float* __restrict__ x,
                                             const float* __restrict__ wl,
                                             const float* __restrict__ bl,
                                             const float* __restrict__ wr,
                                             float* __restrict__ hout) {
    constexpr int R = 8;
    constexpr int NC = C / 128;
    __shared__ __align__(16) float als[R * K];
    __shared__ __align__(16) float xls[R * K];
    __shared__ float red[2];
    int t = threadIdx.x;
    int lane = t & 63, wid = t >> 6;
    int ch = blockIdx.x;  // grid == N_NODES/R
    int base = ch * R * K;
    for (int i = t; i < R * K; i += 128) {
        als[i] = aggr[base + i];
        xls[i] = x[base + i];
    }
    __syncthreads();
    float acc[NC][R];
#pragma unroll
    for (int nc = 0; nc < NC; ++nc) {
        float bv = bl[t + nc * 128];
#pragma unroll
        for (int r = 0; r < R; ++r) acc[nc][r] = bv;
    }
    for (int k4 = 0; k4 < K / 4; ++k4) {
        float4 av[R], xv[R];
#pragma unroll
        for (int r = 0; r < R; ++r) {
            av[r] = *(const float4*)&als[r * K + k4 * 4];
            xv[r] = *(const float4*)&xls[r * K + k4 * 4];
        }
#pragma unroll
        for (int j = 0; j < 4; ++j) {
            int k = k4 * 4 + j;
            float wlv[NC], wrv[NC];
#pragma unroll
            for (int nc = 0; nc < NC; ++nc) {
                wlv[nc] = wl[k * C + t + nc * 128];
                wrv[nc] = wr[k * C + t + nc * 128];
            }
#pragma unroll
            for (int r = 0; r < R; ++r) {
                float a = (j == 0) ? av[r].x : (j == 1) ? av[r].y : (j == 2) ? av[r].z : av[r].w;
                float xr = (j == 0) ? xv[r].x : (j == 1) ? xv[r].y : (j == 2) ? xv[r].z : xv[r].w;
#pragma unroll
                for (int nc = 0; nc < NC; ++nc)
                    acc[nc][r] = fmaf(a, wlv[nc], fmaf(xr, wrv[nc], acc[nc][r]));
            }
        }
    }
#pragma unroll
    for (int r = 0; r < R; ++r) {
        float ss = 0.f;
#pragma unroll
        for (int nc = 0; nc < NC; ++nc) ss += acc[nc][r] * acc[nc][r];
#pragma unroll
        for (int off = 32; off > 0; off >>= 1) ss += __shfl_xor(ss, off);
        if (lane == 0) red[wid] = ss;
        __syncthreads();
        float tot = red[0] + red[1];
        __syncthreads();
        float rinv = 1.f / fmaxf(sqrtf(tot), 1e-12f);
#pragma unroll
        for (int nc = 0; nc < NC; ++nc)
            hout[(ch * R + r) * C + t + nc * 128] = fmaxf(acc[nc][r] * rinv, 0.f);
    }
}

// ---------------- MemPool stage A ----------------
__global__ __launch_bounds__(64) void k_pool_a(const float* __restrict__ h2,
                                               const float* __restrict__ kmem,
                                               const float* __restrict__ wconv,
                                               float* __restrict__ part) {
    __shared__ float kls[16 * 128];
    __shared__ float pool[512];
    __shared__ float kk2s[16];
    int t = threadIdx.x;
    for (int i = t; i < 16 * 128; i += 64) kls[i] = kmem[i];
    for (int i = t; i < 512; i += 64) pool[i] = 0.f;
    __syncthreads();
    if (t < 16) {
        float s = 0.f;
        for (int f = 0; f < 128; ++f) s += kls[t * 128 + f] * kls[t * 128 + f];
        kk2s[t] = s;
    }
    float wc0 = wconv[0], wc1 = wconv[1], wc2 = wconv[2], wc3 = wconv[3];
    __syncthreads();
    for (int n = blockIdx.x; n < N_NODES; n += gridDim.x) {
        float x0 = h2[(size_t)n * 128 + t];
        float x1 = h2[(size_t)n * 128 + 64 + t];
        float arr[17];
#pragma unroll
        for (int k = 0; k < 16; ++k)
            arr[k] = kls[k * 128 + t] * x0 + kls[k * 128 + 64 + t] * x1;
        arr[16] = x0 * x0 + x1 * x1;
#pragma unroll
        for (int off = 32; off > 0; off >>= 1) {
#pragma unroll
            for (int i = 0; i < 17; ++i) arr[i] += __shfl_xor(arr[i], off);
        }
        float x2 = arr[16];
        float dist[16];
#pragma unroll
        for (int k = 0; k < 16; ++k) {
            float d2 = fmaxf(kk2s[k] + x2 - 2.f * arr[k], 0.f);
            dist[k] = 1.f / (1.f + d2);
        }
        float s0 = 0.f, s1 = 0.f, s2 = 0.f, s3 = 0.f;
#pragma unroll
        for (int h = 0; h < 4; ++h) {
            float wch = (h == 0) ? wc0 : (h == 1) ? wc1 : (h == 2) ? wc2 : wc3;
            float den = dist[h * 4] + dist[h * 4 + 1] + dist[h * 4 + 2] + dist[h * 4 + 3];
            float inv = wch / den;
            s0 += dist[h * 4 + 0] * inv;
            s1 += dist[h * 4 + 1] * inv;
            s2 += dist[h * 4 + 2] * inv;
            s3 += dist[h * 4 + 3] * inv;
        }
        float mx = fmaxf(fmaxf(s0, s1), fmaxf(s2, s3));
        float e0 = __expf(s0 - mx), e1 = __expf(s1 - mx), e2 = __expf(s2 - mx), e3 = __expf(s3 - mx);
        float inv = 1.f / (e0 + e1 + e2 + e3);
        e0 *= inv; e1 *= inv; e2 *= inv; e3 *= inv;
        pool[0 * 128 + t]      += e0 * x0; pool[0 * 128 + 64 + t] += e0 * x1;
        pool[1 * 128 + t]      += e1 * x0; pool[1 * 128 + 64 + t] += e1 * x1;
        pool[2 * 128 + t]      += e2 * x0; pool[2 * 128 + 64 + t] += e2 * x1;
        pool[3 * 128 + t]      += e3 * x0; pool[3 * 128 + 64 + t] += e3 * x1;
    }
    __syncthreads();
    for (int i = t; i < 512; i += 64) part[(size_t)blockIdx.x * 512 + i] = pool[i];
}

// ---------------- MemPool stage B ----------------
__global__ __launch_bounds__(256) void k_pool_b(const float* __restrict__ part,
                                                float* __restrict__ pooled) {
    int j = blockIdx.x;  // 0..511
    float s = 0.f;
    for (int b = threadIdx.x; b < POOL_BLOCKS; b += 256) s += part[(size_t)b * 512 + j];
#pragma unroll
    for (int off = 32; off > 0; off >>= 1) s += __shfl_xor(s, off);
    __shared__ float red[4];
    int lane = threadIdx.x & 63, wid = threadIdx.x >> 6;
    if (lane == 0) red[wid] = s;
    __syncthreads();
    if (threadIdx.x == 0) pooled[j] = red[0] + red[1] + red[2] + red[3];
}

// ---------------- head ----------------
__global__ __launch_bounds__(128) void k_final(const float* __restrict__ pooled,
                                               const float* __restrict__ wmem,
                                               const float* __restrict__ bmem,
                                               const float* __restrict__ wfx,
                                               const float* __restrict__ bfx,
                                               const float* __restrict__ gamma,
                                               const float* __restrict__ beta,
                                               float* __restrict__ out) {
    __shared__ float gx[128], g[128];
    int t = threadIdx.x;
    gx[t] = 0.25f * (pooled[t] + pooled[128 + t] + pooled[256 + t] + pooled[384 + t]);
    __syncthreads();
    float acc = bmem[t];
    for (int f = 0; f < 128; ++f) acc = fmaf(gx[f], wmem[f * 128 + t], acc);
    g[t] = acc;
    __syncthreads();
    if (t < 64) {
        float y = bfx[t];
        for (int f = 0; f < 128; ++f) y = fmaf(g[f], wfx[f * 64 + t], y);
        float s = y, s2 = y * y;
#pragma unroll
        for (int off = 32; off > 0; off >>= 1) {
            s += __shfl_xor(s, off);
            s2 += __shfl_xor(s2, off);
        }
        float mu = s * (1.f / 64.f);
        float var = s2 * (1.f / 64.f) - mu * mu;
        float v = (y - mu) / sqrtf(var + 1e-5f) * gamma[t] + beta[t];
        out[t] = fmaxf(v, 0.f);
    }
}

extern "C" void kernel_launch(void* const* d_in, const int* in_sizes, int n_in,
                              void* d_out, int out_size, void* d_ws, size_t ws_size,
                              hipStream_t stream) {
    const float* x        = (const float*)d_in[0];
    const int*   ei       = (const int*)  d_in[1];
    const float* w_proj1  = (const float*)d_in[2];
    const float* b_proj1  = (const float*)d_in[3];
    const float* t1       = (const float*)d_in[4];
    const float* w_l1     = (const float*)d_in[5];
    const float* b_l1     = (const float*)d_in[6];
    const float* w_r1     = (const float*)d_in[7];
    const float* w_proj2  = (const float*)d_in[8];
    const float* b_proj2  = (const float*)d_in[9];
    const float* t2       = (const float*)d_in[10];
    const float* w_l2     = (const float*)d_in[11];
    const float* b_l2     = (const float*)d_in[12];
    const float* w_r2     = (const float*)d_in[13];
    const float* k_mem    = (const float*)d_in[14];
    const float* w_conv   = (const float*)d_in[15];
    const float* w_memlin = (const float*)d_in[16];
    const float* b_memlin = (const float*)d_in[17];
    const float* w_fx     = (const float*)d_in[18];
    const float* b_fx     = (const float*)d_in[19];
    const float* gamma    = (const float*)d_in[20];
    const float* beta     = (const float*)d_in[21];
    const int* src = ei;
    const int* dst = ei + N_EDGES;
    (void)in_sizes; (void)n_in; (void)out_size; (void)ws_size;

    // ---- lifetime-aliased workspace arena (peak ~163 MB) ----
    char* W = (char*)d_ws;
    const size_t MB = 1024 * 1024;
    int*   row_ptr    = (int*)(W + 0);              // 200,004 B
    int*   cursor     = (int*)(W + 256 * 1024);     // 200,000 B (also counts)
    int*   partial    = (int*)(W + 512 * 1024);     // 784 B
    int*   src_sorted = (int*)(W + 768 * 1024);     // 3.2 MB  -> ends < 4 MB
    float* h1     = (float*)(W + 4 * MB);           // 51.2 MB  [4,55.2)   live out1..out2
    float* xp1    = (float*)(W + 56 * MB);          // 12.8 MB  [56,68.8)  dead after aggr1
    float* xp2    = (float*)(W + 56 * MB);          // 51.2 MB  [56,107.2) dead after aggr2
    float* h2     = (float*)(W + 56 * MB);          // 25.6 MB  [56,81.6)  written by out2 (xp2 dead)
    float* aggr1  = (float*)(W + 108 * MB);         // 12.8 MB  dead after out1
    float* aggr2  = (float*)(W + 108 * MB);         // 51.2 MB  [108,159.2) dead after out2
    float* part   = (float*)(W + 4 * MB);           // 4 MB (h1 dead by pool time)
    float* pooled = (float*)(W + 9 * MB);           // 2 KB

    // CSR build
    hipMemsetAsync(cursor, 0, N_NODES * sizeof(int), stream);
    k_hist<<<(N_EDGES + 255) / 256, 256, 0, stream>>>(dst, cursor);
    k_scan1<<<NB, 256, 0, stream>>>(cursor, row_ptr, partial);
    k_scan2<<<1, 256, 0, stream>>>(partial, row_ptr);
    k_scan3<<<NB, 256, 0, stream>>>(row_ptr, partial, cursor);
    k_scatter<<<(N_EDGES + 255) / 256, 256, 0, stream>>>(src, dst, cursor, src_sorted);

    // layer 1
    k_proj<64, 64, 64><<<6250, 64, 0, stream>>>(x, w_proj1, b_proj1, xp1);
    k_aggr<64><<<N_NODES, 64, 0, stream>>>(xp1, t1, row_ptr, src_sorted, aggr1);
    k_out<64, 256><<<6250, 128, 0, stream>>>(aggr1, x, w_l1, b_l1, w_r1, h1);

    // layer 2
    k_proj<256, 256, 128><<<6250, 128, 0, stream>>>(h1, w_proj2, b_proj2, xp2);
    k_aggr<256><<<N_NODES, 256, 0, stream>>>(xp2, t2, row_ptr, src_sorted, aggr2);
    k_out<256, 128><<<6250, 128, 0, stream>>>(aggr2, h1, w_l2, b_l2, w_r2, h2);

    // mempool + head
    k_pool_a<<<POOL_BLOCKS, 64, 0, stream>>>(h2, k_mem, w_conv, part);
    k_pool_b<<<512, 256, 0, stream>>>(part, pooled);
    k_final<<<1, 128, 0, stream>>>(pooled, w_memlin, b_memlin, w_fx, b_fx, gamma, beta,
                                   (float*)d_out);
}

// Round 3
// 543.992 us; speedup vs baseline: 1.5929x; 1.5929x over previous
//
#include <hip/hip_runtime.h>
#include <hip/hip_bf16.h>

#define N_NODES 50000
#define N_EDGES 800000
#define POOL_BLOCKS 2048
#define NB 196  // ceil(N_NODES/256)

typedef __attribute__((ext_vector_type(8))) short short8;
typedef __attribute__((ext_vector_type(4))) float f32x4;

__device__ __forceinline__ float us2f(unsigned short u) {
    return __uint_as_float(((unsigned int)u) << 16);
}
__device__ __forceinline__ unsigned short f2bu(float f) {
    unsigned int u = __float_as_uint(f);
    unsigned int r = (u + 0x7fffu + ((u >> 16) & 1u)) >> 16;  // RNE
    return (unsigned short)r;
}

// ---------------- CSR build ----------------
__global__ void k_hist(const int* __restrict__ dst, int* __restrict__ counts) {
    int e = blockIdx.x * 256 + threadIdx.x;
    if (e < N_EDGES) atomicAdd(&counts[dst[e]], 1);
}

__global__ __launch_bounds__(256) void k_scan1(const int* __restrict__ counts,
                                               int* __restrict__ row_ptr,
                                               int* __restrict__ partial) {
    __shared__ int sd[256];
    int t = threadIdx.x, i = blockIdx.x * 256 + t;
    int v = (i < N_NODES) ? counts[i] : 0;
    sd[t] = v;
    __syncthreads();
    for (int off = 1; off < 256; off <<= 1) {
        int o = (t >= off) ? sd[t - off] : 0;
        __syncthreads();
        sd[t] += o;
        __syncthreads();
    }
    if (i < N_NODES) row_ptr[i] = sd[t] - v;
    if (t == 255) partial[blockIdx.x] = sd[255];
}

__global__ __launch_bounds__(256) void k_scan2(int* __restrict__ partial,
                                               int* __restrict__ row_ptr) {
    __shared__ int sd[256];
    int t = threadIdx.x;
    int v = (t < NB) ? partial[t] : 0;
    sd[t] = v;
    __syncthreads();
    for (int off = 1; off < 256; off <<= 1) {
        int o = (t >= off) ? sd[t - off] : 0;
        __syncthreads();
        sd[t] += o;
        __syncthreads();
    }
    if (t < NB) partial[t] = sd[t] - v;
    if (t == NB - 1) row_ptr[N_NODES] = sd[t];
}

__global__ __launch_bounds__(256) void k_scan3(int* __restrict__ row_ptr,
                                               const int* __restrict__ partial,
                                               int* __restrict__ cursor) {
    int i = blockIdx.x * 256 + threadIdx.x;
    if (i < N_NODES) {
        int v = row_ptr[i] + partial[blockIdx.x];
        row_ptr[i] = v;
        cursor[i] = v;
    }
}

__global__ void k_scatter(const int* __restrict__ src, const int* __restrict__ dst,
                          int* __restrict__ cursor, int* __restrict__ src_sorted) {
    int e = blockIdx.x * 256 + threadIdx.x;
    if (e < N_EDGES) {
        int d = dst[e];
        int pos = atomicAdd(&cursor[d], 1);
        src_sorted[pos] = src[e];
    }
}

// ---------------- weight transpose-cast: dst[n*ldk + koff + k] = bf16(src[k*C + n]) ----------------
__global__ void k_wcast(const float* __restrict__ src, unsigned short* __restrict__ dstp,
                        int Ksub, int Cc, int ldk, int koff) {
    int idx = blockIdx.x * 256 + threadIdx.x;
    if (idx >= Ksub * Cc) return;
    int k = idx / Cc, n = idx % Cc;
    dstp[n * ldk + koff + k] = f2bu(src[k * Cc + n]);
}

// cast x (fp32 [M][64]) into cat1[:,64:128] bf16
__global__ void k_xcast(const float* __restrict__ x, unsigned short* __restrict__ cat1) {
    int idx = blockIdx.x * 256 + threadIdx.x;
    if (idx >= N_NODES * 64) return;
    int i = idx >> 6, j = idx & 63;
    cat1[i * 128 + 64 + j] = f2bu(x[idx]);
}

// ---------------- MFMA bf16 GEMM, 64-row tile, fused epilogue ----------------
// EP: 0 = bias+relu -> bf16 ; 1 = bias+l2norm+relu -> bf16 ; 2 = bias+l2norm+relu -> fp32
template<int K, int C, int LDA, int LDOUT, int OUT_OFF, int EP>
__global__ __launch_bounds__(256) void k_gemm(const unsigned short* __restrict__ A,
                                              const unsigned short* __restrict__ BT,
                                              const float* __restrict__ bias,
                                              void* __restrict__ outv) {
    constexpr int NT = C / 16;
    constexpr int SAE = 64 * 72;       // sA elements (stride 72 kills bank conflicts)
    constexpr int SBE = C * 72;
    constexpr int STAGE_B = (SAE + SBE) * 2;
    constexpr int RP_B = 64 * C * (EP == 2 ? 4 : 2);
    constexpr int SMEM_B = STAGE_B > RP_B ? STAGE_B : RP_B;
    __shared__ __align__(16) char smem[SMEM_B];
    unsigned short* sA = (unsigned short*)smem;
    unsigned short* sB = sA + SAE;

    int t = threadIdx.x;
    int wid = t >> 6, lane = t & 63;
    int lrow = lane & 15, quad = lane >> 4;
    int m0 = blockIdx.x * 64;

    f32x4 acc[NT];
#pragma unroll
    for (int nt = 0; nt < NT; ++nt)
#pragma unroll
        for (int r = 0; r < 4; ++r) acc[nt][r] = 0.f;

    for (int k0 = 0; k0 < K; k0 += 64) {
        __syncthreads();
        // stage A: 64 rows x 64 bf16 = 512 uint4
        for (int i = t; i < 512; i += 256) {
            int r = i >> 3, seg = i & 7;
            int m = m0 + r;
            uint4 v = make_uint4(0u, 0u, 0u, 0u);
            if (m < N_NODES) v = *(const uint4*)&A[(size_t)m * LDA + k0 + seg * 8];
            *(uint4*)&sA[r * 72 + seg * 8] = v;
        }
        // stage B^T: C rows x 64 bf16
        for (int i = t; i < C * 8; i += 256) {
            int n = i >> 3, seg = i & 7;
            uint4 v = *(const uint4*)&BT[(size_t)n * K + k0 + seg * 8];
            *(uint4*)&sB[n * 72 + seg * 8] = v;
        }
        __syncthreads();
#pragma unroll
        for (int kk = 0; kk < 2; ++kk) {
            short8 af = *(const short8*)&sA[(wid * 16 + lrow) * 72 + kk * 32 + quad * 8];
#pragma unroll
            for (int nt = 0; nt < NT; ++nt) {
                short8 bfg = *(const short8*)&sB[(nt * 16 + lrow) * 72 + kk * 32 + quad * 8];
                acc[nt] = __builtin_amdgcn_mfma_f32_16x16x32_bf16(af, bfg, acc[nt], 0, 0, 0);
            }
        }
    }

    // epilogue: bias (+ l2norm) + relu in registers
#pragma unroll
    for (int nt = 0; nt < NT; ++nt) {
        float bv = bias[nt * 16 + lrow];
#pragma unroll
        for (int r = 0; r < 4; ++r) acc[nt][r] += bv;
    }
    if (EP >= 1) {
#pragma unroll
        for (int r = 0; r < 4; ++r) {
            float ss = 0.f;
#pragma unroll
            for (int nt = 0; nt < NT; ++nt) ss += acc[nt][r] * acc[nt][r];
            ss += __shfl_xor(ss, 1);
            ss += __shfl_xor(ss, 2);
            ss += __shfl_xor(ss, 4);
            ss += __shfl_xor(ss, 8);
            float rinv = 1.f / fmaxf(sqrtf(ss), 1e-12f);
#pragma unroll
            for (int nt = 0; nt < NT; ++nt)
                acc[nt][r] = fmaxf(acc[nt][r] * rinv, 0.f);
        }
    } else {
#pragma unroll
        for (int nt = 0; nt < NT; ++nt)
#pragma unroll
            for (int r = 0; r < 4; ++r) acc[nt][r] = fmaxf(acc[nt][r], 0.f);
    }

    __syncthreads();  // all waves done reading sB before repack overwrite
    if (EP == 2) {
        float* rp = (float*)smem;
#pragma unroll
        for (int nt = 0; nt < NT; ++nt)
#pragma unroll
            for (int r = 0; r < 4; ++r)
                rp[(wid * 16 + quad * 4 + r) * C + nt * 16 + lrow] = acc[nt][r];
        __syncthreads();
        float* outp = (float*)outv;
        for (int i = t; i < 64 * C / 4; i += 256) {
            int f = i * 4, r = f / C, c = f % C;
            int m = m0 + r;
            if (m < N_NODES)
                *(float4*)&outp[(size_t)m * LDOUT + OUT_OFF + c] = *(const float4*)&rp[f];
        }
    } else {
        unsigned short* rp = (unsigned short*)smem;
#pragma unroll
        for (int nt = 0; nt < NT; ++nt)
#pragma unroll
            for (int r = 0; r < 4; ++r)
                rp[(wid * 16 + quad * 4 + r) * C + nt * 16 + lrow] = f2bu(acc[nt][r]);
        __syncthreads();
        unsigned short* outp = (unsigned short*)outv;
        for (int i = t; i < 64 * C / 8; i += 256) {
            int f = i * 8, r = f / C, c = f % C;
            int m = m0 + r;
            if (m < N_NODES)
                *(uint4*)&outp[(size_t)m * LDOUT + OUT_OFF + c] = *(const uint4*)&rp[f];
        }
    }
}

// ---------------- segment softmax aggregation, bf16 messages ----------------
// C=256: 64 threads, 4 channels/thread, uint2 loads, 4-edge chunks
__global__ __launch_bounds__(64) void k_aggr256(const unsigned short* __restrict__ xp,
                                                const float* __restrict__ tvec,
                                                const int* __restrict__ row_ptr,
                                                const int* __restrict__ srcs,
                                                unsigned short* __restrict__ outp) {
    int t = threadIdx.x;
    int n = blockIdx.x;
    float tv[4];
#pragma unroll
    for (int j = 0; j < 4; ++j) tv[j] = tvec[t * 4 + j];
    int beg = row_ptr[n], end = row_ptr[n + 1];
    float m[4], se[4], sem[4];
#pragma unroll
    for (int j = 0; j < 4; ++j) { m[j] = -INFINITY; se[j] = 0.f; sem[j] = 0.f; }
    for (int e = beg; e < end; e += 4) {
        int cnt = end - e;
        uint2 v[4];
#pragma unroll
        for (int j = 0; j < 4; ++j) {
            int ee = (j < cnt) ? e + j : e;
            int s = srcs[ee];
            v[j] = *(const uint2*)&xp[(size_t)s * 256 + t * 4];
        }
#pragma unroll
        for (int j = 0; j < 4; ++j) {
            if (j < cnt) {
                float msg[4];
                msg[0] = __uint_as_float(v[j].x << 16);
                msg[1] = __uint_as_float(v[j].x & 0xFFFF0000u);
                msg[2] = __uint_as_float(v[j].y << 16);
                msg[3] = __uint_as_float(v[j].y & 0xFFFF0000u);
#pragma unroll
                for (int c = 0; c < 4; ++c) {
                    float logit = msg[c] * tv[c];
                    float mn = fmaxf(m[c], logit);
                    float sc = __expf(m[c] - mn);
                    float w = __expf(logit - mn);
                    se[c] = se[c] * sc + w;
                    sem[c] = sem[c] * sc + w * msg[c];
                    m[c] = mn;
                }
            }
        }
    }
    ushort4 o;
    o.x = f2bu(sem[0] / fmaxf(se[0], 1e-16f));
    o.y = f2bu(sem[1] / fmaxf(se[1], 1e-16f));
    o.z = f2bu(sem[2] / fmaxf(se[2], 1e-16f));
    o.w = f2bu(sem[3] / fmaxf(se[3], 1e-16f));
    *(ushort4*)&outp[(size_t)n * 512 + t * 4] = o;
}

// C=64: 64 threads, 1 channel/thread, 4-edge chunks
__global__ __launch_bounds__(64) void k_aggr64(const unsigned short* __restrict__ xp,
                                               const float* __restrict__ tvec,
                                               const int* __restrict__ row_ptr,
                                               const int* __restrict__ srcs,
                                               unsigned short* __restrict__ outp) {
    int c = threadIdx.x;
    int n = blockIdx.x;
    float tv = tvec[c];
    int beg = row_ptr[n], end = row_ptr[n + 1];
    float m = -INFINITY, se = 0.f, sem = 0.f;
    for (int e = beg; e < end; e += 4) {
        int cnt = end - e;
        unsigned short v[4];
#pragma unroll
        for (int j = 0; j < 4; ++j) {
            int ee = (j < cnt) ? e + j : e;
            int s = srcs[ee];
            v[j] = xp[(size_t)s * 64 + c];
        }
#pragma unroll
        for (int j = 0; j < 4; ++j) {
            if (j < cnt) {
                float msg = us2f(v[j]);
                float logit = msg * tv;
                float mn = fmaxf(m, logit);
                float sc = __expf(m - mn);
                float w = __expf(logit - mn);
                se = se * sc + w;
                sem = sem * sc + w * msg;
                m = mn;
            }
        }
    }
    outp[(size_t)n * 128 + c] = f2bu(sem / fmaxf(se, 1e-16f));
}

// ---------------- MemPool stage A (h2 fp32) ----------------
__global__ __launch_bounds__(64) void k_pool_a(const float* __restrict__ h2,
                                               const float* __restrict__ kmem,
                                               const float* __restrict__ wconv,
                                               float* __restrict__ part) {
    __shared__ float kls[16 * 128];
    __shared__ float pool[512];
    __shared__ float kk2s[16];
    int t = threadIdx.x;
    for (int i = t; i < 16 * 128; i += 64) kls[i] = kmem[i];
    for (int i = t; i < 512; i += 64) pool[i] = 0.f;
    __syncthreads();
    if (t < 16) {
        float s = 0.f;
        for (int f = 0; f < 128; ++f) s += kls[t * 128 + f] * kls[t * 128 + f];
        kk2s[t] = s;
    }
    float wc0 = wconv[0], wc1 = wconv[1], wc2 = wconv[2], wc3 = wconv[3];
    __syncthreads();
    for (int n = blockIdx.x; n < N_NODES; n += gridDim.x) {
        float x0 = h2[(size_t)n * 128 + t];
        float x1 = h2[(size_t)n * 128 + 64 + t];
        float arr[17];
#pragma unroll
        for (int k = 0; k < 16; ++k)
            arr[k] = kls[k * 128 + t] * x0 + kls[k * 128 + 64 + t] * x1;
        arr[16] = x0 * x0 + x1 * x1;
#pragma unroll
        for (int off = 32; off > 0; off >>= 1) {
#pragma unroll
            for (int i = 0; i < 17; ++i) arr[i] += __shfl_xor(arr[i], off);
        }
        float x2 = arr[16];
        float dist[16];
#pragma unroll
        for (int k = 0; k < 16; ++k) {
            float d2 = fmaxf(kk2s[k] + x2 - 2.f * arr[k], 0.f);
            dist[k] = 1.f / (1.f + d2);
        }
        float s0 = 0.f, s1 = 0.f, s2 = 0.f, s3 = 0.f;
#pragma unroll
        for (int h = 0; h < 4; ++h) {
            float wch = (h == 0) ? wc0 : (h == 1) ? wc1 : (h == 2) ? wc2 : wc3;
            float den = dist[h * 4] + dist[h * 4 + 1] + dist[h * 4 + 2] + dist[h * 4 + 3];
            float inv = wch / den;
            s0 += dist[h * 4 + 0] * inv;
            s1 += dist[h * 4 + 1] * inv;
            s2 += dist[h * 4 + 2] * inv;
            s3 += dist[h * 4 + 3] * inv;
        }
        float mx = fmaxf(fmaxf(s0, s1), fmaxf(s2, s3));
        float e0 = __expf(s0 - mx), e1 = __expf(s1 - mx), e2 = __expf(s2 - mx), e3 = __expf(s3 - mx);
        float inv = 1.f / (e0 + e1 + e2 + e3);
        e0 *= inv; e1 *= inv; e2 *= inv; e3 *= inv;
        pool[0 * 128 + t]      += e0 * x0; pool[0 * 128 + 64 + t] += e0 * x1;
        pool[1 * 128 + t]      += e1 * x0; pool[1 * 128 + 64 + t] += e1 * x1;
        pool[2 * 128 + t]      += e2 * x0; pool[2 * 128 + 64 + t] += e2 * x1;
        pool[3 * 128 + t]      += e3 * x0; pool[3 * 128 + 64 + t] += e3 * x1;
    }
    __syncthreads();
    for (int i = t; i < 512; i += 64) part[(size_t)blockIdx.x * 512 + i] = pool[i];
}

__global__ __launch_bounds__(256) void k_pool_b(const float* __restrict__ part,
                                                float* __restrict__ pooled) {
    int j = blockIdx.x;
    float s = 0.f;
    for (int b = threadIdx.x; b < POOL_BLOCKS; b += 256) s += part[(size_t)b * 512 + j];
#pragma unroll
    for (int off = 32; off > 0; off >>= 1) s += __shfl_xor(s, off);
    __shared__ float red[4];
    int lane = threadIdx.x & 63, wid = threadIdx.x >> 6;
    if (lane == 0) red[wid] = s;
    __syncthreads();
    if (threadIdx.x == 0) pooled[j] = red[0] + red[1] + red[2] + red[3];
}

__global__ __launch_bounds__(128) void k_final(const float* __restrict__ pooled,
                                               const float* __restrict__ wmem,
                                               const float* __restrict__ bmem,
                                               const float* __restrict__ wfx,
                                               const float* __restrict__ bfx,
                                               const float* __restrict__ gamma,
                                               const float* __restrict__ beta,
                                               float* __restrict__ out) {
    __shared__ float gx[128], g[128];
    int t = threadIdx.x;
    gx[t] = 0.25f * (pooled[t] + pooled[128 + t] + pooled[256 + t] + pooled[384 + t]);
    __syncthreads();
    float acc = bmem[t];
    for (int f = 0; f < 128; ++f) acc = fmaf(gx[f], wmem[f * 128 + t], acc);
    g[t] = acc;
    __syncthreads();
    if (t < 64) {
        float y = bfx[t];
        for (int f = 0; f < 128; ++f) y = fmaf(g[f], wfx[f * 64 + t], y);
        float s = y, s2 = y * y;
#pragma unroll
        for (int off = 32; off > 0; off >>= 1) {
            s += __shfl_xor(s, off);
            s2 += __shfl_xor(s2, off);
        }
        float mu = s * (1.f / 64.f);
        float var = s2 * (1.f / 64.f) - mu * mu;
        float v = (y - mu) / sqrtf(var + 1e-5f) * gamma[t] + beta[t];
        out[t] = fmaxf(v, 0.f);
    }
}

extern "C" void kernel_launch(void* const* d_in, const int* in_sizes, int n_in,
                              void* d_out, int out_size, void* d_ws, size_t ws_size,
                              hipStream_t stream) {
    const float* x        = (const float*)d_in[0];
    const int*   ei       = (const int*)  d_in[1];
    const float* w_proj1  = (const float*)d_in[2];
    const float* b_proj1  = (const float*)d_in[3];
    const float* t1       = (const float*)d_in[4];
    const float* w_l1     = (const float*)d_in[5];
    const float* b_l1     = (const float*)d_in[6];
    const float* w_r1     = (const float*)d_in[7];
    const float* w_proj2  = (const float*)d_in[8];
    const float* b_proj2  = (const float*)d_in[9];
    const float* t2       = (const float*)d_in[10];
    const float* w_l2     = (const float*)d_in[11];
    const float* b_l2     = (const float*)d_in[12];
    const float* w_r2     = (const float*)d_in[13];
    const float* k_mem    = (const float*)d_in[14];
    const float* w_conv   = (const float*)d_in[15];
    const float* w_memlin = (const float*)d_in[16];
    const float* b_memlin = (const float*)d_in[17];
    const float* w_fx     = (const float*)d_in[18];
    const float* b_fx     = (const float*)d_in[19];
    const float* gamma    = (const float*)d_in[20];
    const float* beta     = (const float*)d_in[21];
    const int* src = ei;
    const int* dst = ei + N_EDGES;
    (void)in_sizes; (void)n_in; (void)out_size; (void)ws_size;

    char* W = (char*)d_ws;
    const size_t MB = 1024 * 1024;
    int*   row_ptr    = (int*)(W + 0);
    int*   cursor     = (int*)(W + 256 * 1024);
    int*   partial    = (int*)(W + 512 * 1024);
    int*   src_sorted = (int*)(W + 768 * 1024);
    unsigned short* cat1 = (unsigned short*)(W + 4 * MB);    // [M][128]: 0-63 aggr1, 64-127 x
    unsigned short* xp1  = (unsigned short*)(W + 17 * MB);   // [M][64]
    unsigned short* cat2 = (unsigned short*)(W + 24 * MB);   // [M][512]: 0-255 aggr2, 256-511 h1
    unsigned short* xp2  = (unsigned short*)(W + 76 * MB);   // [M][256]
    float* h2     = (float*)(W + 102 * MB);                  // [M][128] fp32
    float* part   = (float*)(W + 128 * MB);
    float* pooled = (float*)(W + 132 * MB);
    unsigned short* B0T  = (unsigned short*)(W + 133 * MB);  // [64][64]
    unsigned short* B1T  = (unsigned short*)(W + 134 * MB);  // [256][128]
    unsigned short* BP2T = (unsigned short*)(W + 135 * MB);  // [256][256]
    unsigned short* B2T  = (unsigned short*)(W + 136 * MB);  // [128][512]

    // CSR build
    hipMemsetAsync(cursor, 0, N_NODES * sizeof(int), stream);
    k_hist<<<(N_EDGES + 255) / 256, 256, 0, stream>>>(dst, cursor);
    k_scan1<<<NB, 256, 0, stream>>>(cursor, row_ptr, partial);
    k_scan2<<<1, 256, 0, stream>>>(partial, row_ptr);
    k_scan3<<<NB, 256, 0, stream>>>(row_ptr, partial, cursor);
    k_scatter<<<(N_EDGES + 255) / 256, 256, 0, stream>>>(src, dst, cursor, src_sorted);

    // weight transpose-casts + x cast
    k_wcast<<<(64 * 64 + 255) / 256, 256, 0, stream>>>(w_proj1, B0T, 64, 64, 64, 0);
    k_wcast<<<(64 * 256 + 255) / 256, 256, 0, stream>>>(w_l1, B1T, 64, 256, 128, 0);
    k_wcast<<<(64 * 256 + 255) / 256, 256, 0, stream>>>(w_r1, B1T, 64, 256, 128, 64);
    k_wcast<<<(256 * 256 + 255) / 256, 256, 0, stream>>>(w_proj2, BP2T, 256, 256, 256, 0);
    k_wcast<<<(256 * 128 + 255) / 256, 256, 0, stream>>>(w_l2, B2T, 256, 128, 512, 0);
    k_wcast<<<(256 * 128 + 255) / 256, 256, 0, stream>>>(w_r2, B2T, 256, 128, 512, 256);
    k_xcast<<<(N_NODES * 64 + 255) / 256, 256, 0, stream>>>(x, cat1);

    const int GB = (N_NODES + 63) / 64;  // 782

    // layer 1
    k_gemm<64, 64, 128, 64, 0, 0><<<GB, 256, 0, stream>>>(cat1 + 64, B0T, b_proj1, xp1);
    k_aggr64<<<N_NODES, 64, 0, stream>>>(xp1, t1, row_ptr, src_sorted, cat1);
    k_gemm<128, 256, 128, 512, 256, 1><<<GB, 256, 0, stream>>>(cat1, B1T, b_l1, cat2);

    // layer 2
    k_gemm<256, 256, 512, 256, 0, 0><<<GB, 256, 0, stream>>>(cat2 + 256, BP2T, b_proj2, xp2);
    k_aggr256<<<N_NODES, 64, 0, stream>>>(xp2, t2, row_ptr, src_sorted, cat2);
    k_gemm<512, 128, 512, 128, 0, 2><<<GB, 256, 0, stream>>>(cat2, B2T, b_l2, h2);

    // mempool + head
    k_pool_a<<<POOL_BLOCKS, 64, 0, stream>>>(h2, k_mem, w_conv, part);
    k_pool_b<<<512, 256, 0, stream>>>(part, pooled);
    k_final<<<1, 128, 0, stream>>>(pooled, w_memlin, b_memlin, w_fx, b_fx, gamma, beta,
                                   (float*)d_out);
}

// Round 4
// 463.390 us; speedup vs baseline: 1.8700x; 1.1739x over previous
//
#include <hip/hip_runtime.h>
#include <hip/hip_bf16.h>

#define N_NODES 50000
#define N_EDGES 800000
#define NB 196  // ceil(N_NODES/256)

typedef __attribute__((ext_vector_type(8))) short short8;
typedef __attribute__((ext_vector_type(4))) float f32x4;

__device__ __forceinline__ float us2f(unsigned short u) {
    return __uint_as_float(((unsigned int)u) << 16);
}
__device__ __forceinline__ unsigned short f2bu(float f) {
    unsigned int u = __float_as_uint(f);
    unsigned int r = (u + 0x7fffu + ((u >> 16) & 1u)) >> 16;  // RNE
    return (unsigned short)r;
}

// ---------------- CSR build ----------------
__global__ void k_hist(const int* __restrict__ dst, int* __restrict__ counts) {
    int e = blockIdx.x * 256 + threadIdx.x;
    if (e < N_EDGES) atomicAdd(&counts[dst[e]], 1);
}

__global__ __launch_bounds__(256) void k_scan1(const int* __restrict__ counts,
                                               int* __restrict__ row_ptr,
                                               int* __restrict__ partial) {
    __shared__ int sd[256];
    int t = threadIdx.x, i = blockIdx.x * 256 + t;
    int v = (i < N_NODES) ? counts[i] : 0;
    sd[t] = v;
    __syncthreads();
    for (int off = 1; off < 256; off <<= 1) {
        int o = (t >= off) ? sd[t - off] : 0;
        __syncthreads();
        sd[t] += o;
        __syncthreads();
    }
    if (i < N_NODES) row_ptr[i] = sd[t] - v;
    if (t == 255) partial[blockIdx.x] = sd[255];
}

__global__ __launch_bounds__(256) void k_scan2(int* __restrict__ partial,
                                               int* __restrict__ row_ptr) {
    __shared__ int sd[256];
    int t = threadIdx.x;
    int v = (t < NB) ? partial[t] : 0;
    sd[t] = v;
    __syncthreads();
    for (int off = 1; off < 256; off <<= 1) {
        int o = (t >= off) ? sd[t - off] : 0;
        __syncthreads();
        sd[t] += o;
        __syncthreads();
    }
    if (t < NB) partial[t] = sd[t] - v;
    if (t == NB - 1) row_ptr[N_NODES] = sd[t];
}

__global__ __launch_bounds__(256) void k_scan3(int* __restrict__ row_ptr,
                                               const int* __restrict__ partial,
                                               int* __restrict__ cursor) {
    int i = blockIdx.x * 256 + threadIdx.x;
    if (i < N_NODES) {
        int v = row_ptr[i] + partial[blockIdx.x];
        row_ptr[i] = v;
        cursor[i] = v;
    }
}

__global__ void k_scatter(const int* __restrict__ src, const int* __restrict__ dst,
                          int* __restrict__ cursor, int* __restrict__ src_sorted) {
    int e = blockIdx.x * 256 + threadIdx.x;
    if (e < N_EDGES) {
        int d = dst[e];
        int pos = atomicAdd(&cursor[d], 1);
        src_sorted[pos] = src[e];
    }
}

// ---------------- weight transpose-cast ----------------
__global__ void k_wcast(const float* __restrict__ src, unsigned short* __restrict__ dstp,
                        int Ksub, int Cc, int ldk, int koff) {
    int idx = blockIdx.x * 256 + threadIdx.x;
    if (idx >= Ksub * Cc) return;
    int k = idx / Cc, n = idx % Cc;
    dstp[n * ldk + koff + k] = f2bu(src[k * Cc + n]);
}

__global__ void k_xcast(const float* __restrict__ x, unsigned short* __restrict__ cat1) {
    int idx = blockIdx.x * 256 + threadIdx.x;
    if (idx >= N_NODES * 64) return;
    int i = idx >> 6, j = idx & 63;
    cat1[i * 128 + 64 + j] = f2bu(x[idx]);
}

// ---------------- MFMA bf16 GEMM, 64-row tile, fused epilogue ----------------
// EP: 0 = bias+relu -> bf16 ; 1 = bias+l2norm+relu -> bf16 ; 2 = bias+l2norm+relu -> fp32
template<int K, int C, int LDA, int LDOUT, int OUT_OFF, int EP>
__global__ __launch_bounds__(256) void k_gemm(const unsigned short* __restrict__ A,
                                              const unsigned short* __restrict__ BT,
                                              const float* __restrict__ bias,
                                              void* __restrict__ outv) {
    constexpr int NT = C / 16;
    constexpr int SAE = 64 * 72;
    constexpr int SBE = C * 72;
    constexpr int STAGE_B = (SAE + SBE) * 2;
    constexpr int RP_B = 64 * C * (EP == 2 ? 4 : 2);
    constexpr int SMEM_B = STAGE_B > RP_B ? STAGE_B : RP_B;
    __shared__ __align__(16) char smem[SMEM_B];
    unsigned short* sA = (unsigned short*)smem;
    unsigned short* sB = sA + SAE;

    int t = threadIdx.x;
    int wid = t >> 6, lane = t & 63;
    int lrow = lane & 15, quad = lane >> 4;
    int m0 = blockIdx.x * 64;

    f32x4 acc[NT];
#pragma unroll
    for (int nt = 0; nt < NT; ++nt)
#pragma unroll
        for (int r = 0; r < 4; ++r) acc[nt][r] = 0.f;

    for (int k0 = 0; k0 < K; k0 += 64) {
        __syncthreads();
        for (int i = t; i < 512; i += 256) {
            int r = i >> 3, seg = i & 7;
            int m = m0 + r;
            uint4 v = make_uint4(0u, 0u, 0u, 0u);
            if (m < N_NODES) v = *(const uint4*)&A[(size_t)m * LDA + k0 + seg * 8];
            *(uint4*)&sA[r * 72 + seg * 8] = v;
        }
        for (int i = t; i < C * 8; i += 256) {
            int n = i >> 3, seg = i & 7;
            uint4 v = *(const uint4*)&BT[(size_t)n * K + k0 + seg * 8];
            *(uint4*)&sB[n * 72 + seg * 8] = v;
        }
        __syncthreads();
#pragma unroll
        for (int kk = 0; kk < 2; ++kk) {
            short8 af = *(const short8*)&sA[(wid * 16 + lrow) * 72 + kk * 32 + quad * 8];
#pragma unroll
            for (int nt = 0; nt < NT; ++nt) {
                short8 bfg = *(const short8*)&sB[(nt * 16 + lrow) * 72 + kk * 32 + quad * 8];
                acc[nt] = __builtin_amdgcn_mfma_f32_16x16x32_bf16(af, bfg, acc[nt], 0, 0, 0);
            }
        }
    }

#pragma unroll
    for (int nt = 0; nt < NT; ++nt) {
        float bv = bias[nt * 16 + lrow];
#pragma unroll
        for (int r = 0; r < 4; ++r) acc[nt][r] += bv;
    }
    if (EP >= 1) {
#pragma unroll
        for (int r = 0; r < 4; ++r) {
            float ss = 0.f;
#pragma unroll
            for (int nt = 0; nt < NT; ++nt) ss += acc[nt][r] * acc[nt][r];
            ss += __shfl_xor(ss, 1);
            ss += __shfl_xor(ss, 2);
            ss += __shfl_xor(ss, 4);
            ss += __shfl_xor(ss, 8);
            float rinv = 1.f / fmaxf(sqrtf(ss), 1e-12f);
#pragma unroll
            for (int nt = 0; nt < NT; ++nt)
                acc[nt][r] = fmaxf(acc[nt][r] * rinv, 0.f);
        }
    } else {
#pragma unroll
        for (int nt = 0; nt < NT; ++nt)
#pragma unroll
            for (int r = 0; r < 4; ++r) acc[nt][r] = fmaxf(acc[nt][r], 0.f);
    }

    __syncthreads();
    if (EP == 2) {
        float* rp = (float*)smem;
#pragma unroll
        for (int nt = 0; nt < NT; ++nt)
#pragma unroll
            for (int r = 0; r < 4; ++r)
                rp[(wid * 16 + quad * 4 + r) * C + nt * 16 + lrow] = acc[nt][r];
        __syncthreads();
        float* outp = (float*)outv;
        for (int i = t; i < 64 * C / 4; i += 256) {
            int f = i * 4, r = f / C, c = f % C;
            int m = m0 + r;
            if (m < N_NODES)
                *(float4*)&outp[(size_t)m * LDOUT + OUT_OFF + c] = *(const float4*)&rp[f];
        }
    } else {
        unsigned short* rp = (unsigned short*)smem;
#pragma unroll
        for (int nt = 0; nt < NT; ++nt)
#pragma unroll
            for (int r = 0; r < 4; ++r)
                rp[(wid * 16 + quad * 4 + r) * C + nt * 16 + lrow] = f2bu(acc[nt][r]);
        __syncthreads();
        unsigned short* outp = (unsigned short*)outv;
        for (int i = t; i < 64 * C / 8; i += 256) {
            int f = i * 8, r = f / C, c = f % C;
            int m = m0 + r;
            if (m < N_NODES)
                *(uint4*)&outp[(size_t)m * LDOUT + OUT_OFF + c] = *(const uint4*)&rp[f];
        }
    }
}

// ---------------- segment softmax aggregation, bf16 messages, max-free ----------------
// msgs are post-ReLU (>=0) and |t|~1 so logits are small: exp() cannot overflow fp32.
// softmax is shift-invariant -> identical result to reference's max-subtracted form.
__global__ __launch_bounds__(256) void k_aggr256(const unsigned short* __restrict__ xp,
                                                 const float* __restrict__ tvec,
                                                 const int* __restrict__ row_ptr,
                                                 const int* __restrict__ srcs,
                                                 unsigned short* __restrict__ outp) {
    int t = threadIdx.x & 63, wid = threadIdx.x >> 6;
    int n = blockIdx.x * 4 + wid;
    if (n >= N_NODES) return;
    float4 tv4 = *(const float4*)&tvec[t * 4];
    float tv[4] = {tv4.x, tv4.y, tv4.z, tv4.w};
    int beg = row_ptr[n], end = row_ptr[n + 1];
    float se[4] = {0.f, 0.f, 0.f, 0.f}, sem[4] = {0.f, 0.f, 0.f, 0.f};
    int e = beg;
    for (; e + 4 <= end; e += 4) {
        uint2 v[4];
#pragma unroll
        for (int j = 0; j < 4; ++j) {
            int s = srcs[e + j];
            v[j] = *(const uint2*)&xp[(size_t)s * 256 + t * 4];
        }
#pragma unroll
        for (int j = 0; j < 4; ++j) {
            float msg[4];
            msg[0] = __uint_as_float(v[j].x << 16);
            msg[1] = __uint_as_float(v[j].x & 0xFFFF0000u);
            msg[2] = __uint_as_float(v[j].y << 16);
            msg[3] = __uint_as_float(v[j].y & 0xFFFF0000u);
#pragma unroll
            for (int c = 0; c < 4; ++c) {
                float w = __expf(msg[c] * tv[c]);
                se[c] += w;
                sem[c] = fmaf(w, msg[c], sem[c]);
            }
        }
    }
    for (; e < end; ++e) {
        int s = srcs[e];
        uint2 v = *(const uint2*)&xp[(size_t)s * 256 + t * 4];
        float msg[4];
        msg[0] = __uint_as_float(v.x << 16);
        msg[1] = __uint_as_float(v.x & 0xFFFF0000u);
        msg[2] = __uint_as_float(v.y << 16);
        msg[3] = __uint_as_float(v.y & 0xFFFF0000u);
#pragma unroll
        for (int c = 0; c < 4; ++c) {
            float w = __expf(msg[c] * tv[c]);
            se[c] += w;
            sem[c] = fmaf(w, msg[c], sem[c]);
        }
    }
    ushort4 o;
    o.x = f2bu(sem[0] / fmaxf(se[0], 1e-16f));
    o.y = f2bu(sem[1] / fmaxf(se[1], 1e-16f));
    o.z = f2bu(sem[2] / fmaxf(se[2], 1e-16f));
    o.w = f2bu(sem[3] / fmaxf(se[3], 1e-16f));
    *(ushort4*)&outp[(size_t)n * 512 + t * 4] = o;
}

__global__ __launch_bounds__(256) void k_aggr64(const unsigned short* __restrict__ xp,
                                                const float* __restrict__ tvec,
                                                const int* __restrict__ row_ptr,
                                                const int* __restrict__ srcs,
                                                unsigned short* __restrict__ outp) {
    int c = threadIdx.x & 63, wid = threadIdx.x >> 6;
    int n = blockIdx.x * 4 + wid;
    if (n >= N_NODES) return;
    float tv = tvec[c];
    int beg = row_ptr[n], end = row_ptr[n + 1];
    float se = 0.f, sem = 0.f;
    int e = beg;
    for (; e + 8 <= end; e += 8) {
        unsigned short v[8];
#pragma unroll
        for (int j = 0; j < 8; ++j) {
            int s = srcs[e + j];
            v[j] = xp[(size_t)s * 64 + c];
        }
#pragma unroll
        for (int j = 0; j < 8; ++j) {
            float msg = us2f(v[j]);
            float w = __expf(msg * tv);
            se += w;
            sem = fmaf(w, msg, sem);
        }
    }
    for (; e < end; ++e) {
        int s = srcs[e];
        float msg = us2f(xp[(size_t)s * 64 + c]);
        float w = __expf(msg * tv);
        se += w;
        sem = fmaf(w, msg, sem);
    }
    outp[(size_t)n * 128 + c] = f2bu(sem / fmaxf(se, 1e-16f));
}

// ---------------- MemPool phase 1: per-node assignment S[n][4] ----------------
__global__ __launch_bounds__(64) void k_pool_s(const float* __restrict__ h2,
                                               const float* __restrict__ kmem,
                                               const float* __restrict__ wconv,
                                               float* __restrict__ S) {
    __shared__ float kls[2048];
    __shared__ float kk2s[16];
    int t = threadIdx.x;
    for (int i = t; i < 2048; i += 64) kls[i] = kmem[i];
    __syncthreads();
    if (t < 16) {
        float s = 0.f;
        for (int f = 0; f < 128; ++f) { float v = kls[t * 128 + f]; s += v * v; }
        kk2s[t] = s;
    }
    __syncthreads();
    int n = blockIdx.x * 64 + t;
    if (n >= N_NODES) return;
    float dots[16];
#pragma unroll
    for (int k = 0; k < 16; ++k) dots[k] = 0.f;
    float x2 = 0.f;
    for (int c = 0; c < 32; ++c) {
        float4 xv = *(const float4*)&h2[(size_t)n * 128 + c * 4];
        x2 += xv.x * xv.x + xv.y * xv.y + xv.z * xv.z + xv.w * xv.w;
#pragma unroll
        for (int k = 0; k < 16; ++k) {
            float4 kv = *(const float4*)&kls[k * 128 + c * 4];
            dots[k] += xv.x * kv.x + xv.y * kv.y + xv.z * kv.z + xv.w * kv.w;
        }
    }
    float dist[16];
#pragma unroll
    for (int k = 0; k < 16; ++k) {
        float d2 = fmaxf(kk2s[k] + x2 - 2.f * dots[k], 0.f);
        dist[k] = 1.f / (1.f + d2);
    }
    float s0 = 0.f, s1 = 0.f, s2 = 0.f, s3 = 0.f;
#pragma unroll
    for (int h = 0; h < 4; ++h) {
        float den = dist[h * 4] + dist[h * 4 + 1] + dist[h * 4 + 2] + dist[h * 4 + 3];
        float inv = wconv[h] / den;
        s0 += dist[h * 4 + 0] * inv;
        s1 += dist[h * 4 + 1] * inv;
        s2 += dist[h * 4 + 2] * inv;
        s3 += dist[h * 4 + 3] * inv;
    }
    float mx = fmaxf(fmaxf(s0, s1), fmaxf(s2, s3));
    float e0 = __expf(s0 - mx), e1 = __expf(s1 - mx), e2 = __expf(s2 - mx), e3 = __expf(s3 - mx);
    float inv = 1.f / (e0 + e1 + e2 + e3);
    float4 o = make_float4(e0 * inv, e1 * inv, e2 * inv, e3 * inv);
    *(float4*)&S[(size_t)n * 4] = o;
}

// ---------------- MemPool phase 2: partial S^T h2 over 256 slices ----------------
__global__ __launch_bounds__(256) void k_pool_c(const float* __restrict__ h2,
                                                const float* __restrict__ Sm,
                                                float* __restrict__ part) {
    int t = threadIdx.x;
    int c = t & 127, sub = t >> 7;
    int slice = blockIdx.x * 2 + sub;  // 0..255
    float a0 = 0.f, a1 = 0.f, a2 = 0.f, a3 = 0.f;
    for (int n = slice; n < N_NODES; n += 256) {
        float xv = h2[(size_t)n * 128 + c];
        float4 sv = *(const float4*)&Sm[(size_t)n * 4];
        a0 = fmaf(sv.x, xv, a0);
        a1 = fmaf(sv.y, xv, a1);
        a2 = fmaf(sv.z, xv, a2);
        a3 = fmaf(sv.w, xv, a3);
    }
    float* p = &part[(size_t)slice * 512];
    p[0 * 128 + c] = a0;
    p[1 * 128 + c] = a1;
    p[2 * 128 + c] = a2;
    p[3 * 128 + c] = a3;
}

// ---------------- MemPool phase 3: reduce 256 slices ----------------
__global__ __launch_bounds__(256) void k_pool_b(const float* __restrict__ part,
                                                float* __restrict__ pooled) {
    int j = blockIdx.x;  // 0..511
    float s = part[(size_t)threadIdx.x * 512 + j];
#pragma unroll
    for (int off = 32; off > 0; off >>= 1) s += __shfl_xor(s, off);
    __shared__ float red[4];
    int lane = threadIdx.x & 63, wid = threadIdx.x >> 6;
    if (lane == 0) red[wid] = s;
    __syncthreads();
    if (threadIdx.x == 0) pooled[j] = red[0] + red[1] + red[2] + red[3];
}

__global__ __launch_bounds__(128) void k_final(const float* __restrict__ pooled,
                                               const float* __restrict__ wmem,
                                               const float* __restrict__ bmem,
                                               const float* __restrict__ wfx,
                                               const float* __restrict__ bfx,
                                               const float* __restrict__ gamma,
                                               const float* __restrict__ beta,
                                               float* __restrict__ out) {
    __shared__ float gx[128], g[128];
    int t = threadIdx.x;
    gx[t] = 0.25f * (pooled[t] + pooled[128 + t] + pooled[256 + t] + pooled[384 + t]);
    __syncthreads();
    float acc = bmem[t];
    for (int f = 0; f < 128; ++f) acc = fmaf(gx[f], wmem[f * 128 + t], acc);
    g[t] = acc;
    __syncthreads();
    if (t < 64) {
        float y = bfx[t];
        for (int f = 0; f < 128; ++f) y = fmaf(g[f], wfx[f * 64 + t], y);
        float s = y, s2 = y * y;
#pragma unroll
        for (int off = 32; off > 0; off >>= 1) {
            s += __shfl_xor(s, off);
            s2 += __shfl_xor(s2, off);
        }
        float mu = s * (1.f / 64.f);
        float var = s2 * (1.f / 64.f) - mu * mu;
        float v = (y - mu) / sqrtf(var + 1e-5f) * gamma[t] + beta[t];
        out[t] = fmaxf(v, 0.f);
    }
}

extern "C" void kernel_launch(void* const* d_in, const int* in_sizes, int n_in,
                              void* d_out, int out_size, void* d_ws, size_t ws_size,
                              hipStream_t stream) {
    const float* x        = (const float*)d_in[0];
    const int*   ei       = (const int*)  d_in[1];
    const float* w_proj1  = (const float*)d_in[2];
    const float* b_proj1  = (const float*)d_in[3];
    const float* t1       = (const float*)d_in[4];
    const float* w_l1     = (const float*)d_in[5];
    const float* b_l1     = (const float*)d_in[6];
    const float* w_r1     = (const float*)d_in[7];
    const float* w_proj2  = (const float*)d_in[8];
    const float* b_proj2  = (const float*)d_in[9];
    const float* t2       = (const float*)d_in[10];
    const float* w_l2     = (const float*)d_in[11];
    const float* b_l2     = (const float*)d_in[12];
    const float* w_r2     = (const float*)d_in[13];
    const float* k_mem    = (const float*)d_in[14];
    const float* w_conv   = (const float*)d_in[15];
    const float* w_memlin = (const float*)d_in[16];
    const float* b_memlin = (const float*)d_in[17];
    const float* w_fx     = (const float*)d_in[18];
    const float* b_fx     = (const float*)d_in[19];
    const float* gamma    = (const float*)d_in[20];
    const float* beta     = (const float*)d_in[21];
    const int* src = ei;
    const int* dst = ei + N_EDGES;
    (void)in_sizes; (void)n_in; (void)out_size; (void)ws_size;

    char* W = (char*)d_ws;
    const size_t MB = 1024 * 1024;
    int*   row_ptr    = (int*)(W + 0);
    int*   cursor     = (int*)(W + 256 * 1024);
    int*   partial    = (int*)(W + 512 * 1024);
    int*   src_sorted = (int*)(W + 768 * 1024);
    unsigned short* cat1 = (unsigned short*)(W + 4 * MB);    // [M][128]: 0-63 aggr1, 64-127 x
    unsigned short* xp1  = (unsigned short*)(W + 17 * MB);   // [M][64]
    unsigned short* cat2 = (unsigned short*)(W + 24 * MB);   // [M][512]: 0-255 aggr2, 256-511 h1
    unsigned short* xp2  = (unsigned short*)(W + 76 * MB);   // [M][256]
    float* h2     = (float*)(W + 102 * MB);                  // [M][128] fp32
    float* Sm     = (float*)(W + 128 * MB);                  // [M][4]
    float* part   = (float*)(W + 130 * MB);                  // [256][512]
    float* pooled = (float*)(W + 131 * MB);
    unsigned short* B0T  = (unsigned short*)(W + 133 * MB);  // [64][64]
    unsigned short* B1T  = (unsigned short*)(W + 134 * MB);  // [256][128]
    unsigned short* BP2T = (unsigned short*)(W + 135 * MB);  // [256][256]
    unsigned short* B2T  = (unsigned short*)(W + 136 * MB);  // [128][512]

    // CSR build
    hipMemsetAsync(cursor, 0, N_NODES * sizeof(int), stream);
    k_hist<<<(N_EDGES + 255) / 256, 256, 0, stream>>>(dst, cursor);
    k_scan1<<<NB, 256, 0, stream>>>(cursor, row_ptr, partial);
    k_scan2<<<1, 256, 0, stream>>>(partial, row_ptr);
    k_scan3<<<NB, 256, 0, stream>>>(row_ptr, partial, cursor);
    k_scatter<<<(N_EDGES + 255) / 256, 256, 0, stream>>>(src, dst, cursor, src_sorted);

    // weight transpose-casts + x cast
    k_wcast<<<(64 * 64 + 255) / 256, 256, 0, stream>>>(w_proj1, B0T, 64, 64, 64, 0);
    k_wcast<<<(64 * 256 + 255) / 256, 256, 0, stream>>>(w_l1, B1T, 64, 256, 128, 0);
    k_wcast<<<(64 * 256 + 255) / 256, 256, 0, stream>>>(w_r1, B1T, 64, 256, 128, 64);
    k_wcast<<<(256 * 256 + 255) / 256, 256, 0, stream>>>(w_proj2, BP2T, 256, 256, 256, 0);
    k_wcast<<<(256 * 128 + 255) / 256, 256, 0, stream>>>(w_l2, B2T, 256, 128, 512, 0);
    k_wcast<<<(256 * 128 + 255) / 256, 256, 0, stream>>>(w_r2, B2T, 256, 128, 512, 256);
    k_xcast<<<(N_NODES * 64 + 255) / 256, 256, 0, stream>>>(x, cat1);

    const int GB = (N_NODES + 63) / 64;   // 782
    const int GA = (N_NODES + 3) / 4;     // 12500

    // layer 1
    k_gemm<64, 64, 128, 64, 0, 0><<<GB, 256, 0, stream>>>(cat1 + 64, B0T, b_proj1, xp1);
    k_aggr64<<<GA, 256, 0, stream>>>(xp1, t1, row_ptr, src_sorted, cat1);
    k_gemm<128, 256, 128, 512, 256, 1><<<GB, 256, 0, stream>>>(cat1, B1T, b_l1, cat2);

    // layer 2
    k_gemm<256, 256, 512, 256, 0, 0><<<GB, 256, 0, stream>>>(cat2 + 256, BP2T, b_proj2, xp2);
    k_aggr256<<<GA, 256, 0, stream>>>(xp2, t2, row_ptr, src_sorted, cat2);
    k_gemm<512, 128, 512, 128, 0, 2><<<GB, 256, 0, stream>>>(cat2, B2T, b_l2, h2);

    // mempool + head
    k_pool_s<<<GB, 64, 0, stream>>>(h2, k_mem, w_conv, Sm);
    k_pool_c<<<128, 256, 0, stream>>>(h2, Sm, part);
    k_pool_b<<<512, 256, 0, stream>>>(part, pooled);
    k_final<<<1, 128, 0, stream>>>(pooled, w_memlin, b_memlin, w_fx, b_fx, gamma, beta,
                                   (float*)d_out);
}